// Round 7
// baseline (177.928 us; speedup 1.0000x reference)
//
#include <hip/hip_runtime.h>
#include <hip/hip_cooperative_groups.h>

namespace cg = cooperative_groups;

#define B_PATHS 32768
#define N_STEPS 50
#define H 64
#define NS 256             // table points per step; 50*256*4 = 50 KB LDS
#define NBLK 512           // cooperative grid: 512 blocks x 64 thr; 2/CU (LDS cap 3/CU)
#define EPB 25             // table evals per block: 512*25 = 50*256

static __device__ __forceinline__ float gelu_f(float x) {
    // tanh-form GELU: max abs err vs exact-erf ~2e-4
    float x2 = x * x;
    float u  = x * fmaf(x2, 0.044715f * 0.7978845608f, 0.7978845608f);
    float e  = exp2f(u * -2.885390081777927f);   // e^{-2u}
    return x / (1.0f + e);
}

static __device__ __forceinline__ float sigmoid_f(float x) {
    float e = exp2f(x * -1.4426950408889634f);
    return 1.0f / (1.0f + e);
}

// Analytic per-step S envelope (covers 32k-path extremes ~4.2 sigma with 8-sigma bound).
static __device__ __forceinline__ void step_range(int i, float& lo, float& hi) {
    const float sd = 0.2f * 0.14142135623f;     // SIGMA * sqrt(DT)
    float w = fmaf(8.0f * sd, sqrtf((float)i), 0.05f);
    lo = 100.0f * expf(-w);
    hi = 100.0f * expf(w);
}

// N independent wave-sum butterflies, stage-interleaved: swizzle latency paid once
// per stage (N in flight), not once per eval.
template <int N>
static __device__ __forceinline__ void wave_sumN(float (&v)[N]) {
    #pragma unroll
    for (int off = 32; off > 0; off >>= 1) {
        float t[N];
        #pragma unroll
        for (int e = 0; e < N; e++) t[e] = __shfl_xor(v[e], off, 64);
        #pragma unroll
        for (int e = 0; e < N; e++) v[e] += t[e];
    }
}

static __device__ __forceinline__ float lane_bcast(float x, int k) {
    return __int_as_float(__builtin_amdgcn_readlane(__float_as_int(x), k));
}

// Evaluate N consecutive table points [gbase, gbase+N) and store them.
// Weight-stationary: lane n owns neuron n; W2 column n in w2c (VGPRs, caller-loaded).
template <int N>
static __device__ __forceinline__ void eval_store(
    int lane, int gbase,
    float w1a, float w1b, float bb1, float gg1, float bbe1,
    float bb2, float gg2, float bbe2, float w3, float b3s,
    const float (&w2c)[H], float* __restrict__ table)
{
    // ---- layer 1 ----
    float h[N], s1[N];
    #pragma unroll
    for (int e = 0; e < N; e++) {
        int idx = gbase + e;
        int i = idx >> 8, j = idx & (NS - 1);
        float lo, hi;
        step_range(i, lo, hi);
        float s  = fmaf((hi - lo) * (1.0f / (float)(NS - 1)), (float)j, lo);
        float x1 = (float)i * 0.02f;     // == t_grid row values, bit-exact
        h[e] = fmaf(s * 0.01f, w1a, fmaf(x1, w1b, bb1));
        s1[e] = h[e];
    }
    wave_sumN<N>(s1);
    float d[N], vv[N];
    #pragma unroll
    for (int e = 0; e < N; e++) { d[e] = h[e] - s1[e] * (1.0f / H); vv[e] = d[e] * d[e]; }
    wave_sumN<N>(vv);
    float hg[N];
    #pragma unroll
    for (int e = 0; e < N; e++) {
        float rstd = rsqrtf(fmaf(vv[e], 1.0f / H, 1e-5f));
        hg[e] = gelu_f(fmaf(d[e] * rstd, gg1, bbe1));
    }

    // ---- layer 2: h2[e]_n = sum_k hg[e]_k * W2[k][n] (readlane -> SGPR fma operand) ----
    float a0[N], a1[N];
    #pragma unroll
    for (int e = 0; e < N; e++) { a0[e] = 0.0f; a1[e] = 0.0f; }
    #pragma unroll
    for (int k = 0; k < H; k += 2) {
        #pragma unroll
        for (int e = 0; e < N; e++) a0[e] = fmaf(lane_bcast(hg[e], k),     w2c[k],     a0[e]);
        #pragma unroll
        for (int e = 0; e < N; e++) a1[e] = fmaf(lane_bcast(hg[e], k + 1), w2c[k + 1], a1[e]);
    }
    float h2[N], s2[N];
    #pragma unroll
    for (int e = 0; e < N; e++) { h2[e] = (a0[e] + a1[e]) + bb2; s2[e] = h2[e]; }

    // ---- LN2 + gelu + layer 3 + sigmoid ----
    wave_sumN<N>(s2);
    float d2[N], v2[N];
    #pragma unroll
    for (int e = 0; e < N; e++) { d2[e] = h2[e] - s2[e] * (1.0f / H); v2[e] = d2[e] * d2[e]; }
    wave_sumN<N>(v2);
    float zf[N];
    #pragma unroll
    for (int e = 0; e < N; e++) {
        float rstd = rsqrtf(fmaf(v2[e], 1.0f / H, 1e-5f));
        zf[e] = gelu_f(fmaf(d2[e] * rstd, gg2, bbe2)) * w3;
    }
    wave_sumN<N>(zf);

    // lane e stores eval e (select chain avoids runtime-indexed register array)
    float zo = sigmoid_f(zf[0] + b3s);
    #pragma unroll
    for (int e = 1; e < N; e++) {
        float z = sigmoid_f(zf[e] + b3s);
        zo = (lane == e) ? z : zo;
    }
    if (lane < N) table[gbase + lane] = zo;
}

// ---------------- fused: table build -> grid sync -> path simulation ----------------
__global__ __launch_bounds__(64) void fused_kernel(
    const float* __restrict__ dw,
    const float* __restrict__ W1, const float* __restrict__ b1,
    const float* __restrict__ g1, const float* __restrict__ be1,
    const float* __restrict__ W2, const float* __restrict__ b2,
    const float* __restrict__ g2, const float* __restrict__ be2,
    const float* __restrict__ W3, const float* __restrict__ b3,
    const float* __restrict__ Y0,
    float* __restrict__ table, float* __restrict__ out)
{
    __shared__ float stab[N_STEPS * NS];   // 50 KB

    int lane = threadIdx.x;

    // ---- table phase: this block's 25 evals, weight-stationary ----
    {
        float w1a = W1[lane], w1b = W1[H + lane], bb1 = b1[lane];
        float gg1 = g1[lane], bbe1 = be1[lane];
        float bb2 = b2[lane], gg2 = g2[lane], bbe2 = be2[lane];
        float w3  = W3[lane];
        float b3s = b3[0];

        float w2c[H];                    // W2 column `lane`: coalesced row loads, once
        #pragma unroll
        for (int k = 0; k < H; k++) w2c[k] = W2[k * H + lane];

        int gbase = blockIdx.x * EPB;
        eval_store<13>(lane, gbase,      w1a, w1b, bb1, gg1, bbe1, bb2, gg2, bbe2, w3, b3s, w2c, table);
        eval_store<12>(lane, gbase + 13, w1a, w1b, bb1, gg1, bbe1, bb2, gg2, bbe2, w3, b3s, w2c, table);
    }

    cg::this_grid().sync();              // table visible device-wide; L2 hot

    // ---- sim phase ----
    const float4* tg = (const float4*)table;
    float4* ts = (float4*)stab;
    #pragma unroll
    for (int q = 0; q < (N_STEPS * NS / 4) / 64; q++)   // 50 float4 per lane
        ts[q * 64 + lane] = tg[q * 64 + lane];
    __syncthreads();

    int p = blockIdx.x * 64 + lane;
    const float rdt = 0.05f * 0.02f;
    const float nsm1 = (float)(NS - 1);

    float dwl[N_STEPS];
    const float2* dw2 = (const float2*)(dw + p * N_STEPS);
    #pragma unroll
    for (int q = 0; q < N_STEPS / 2; q++) {
        float2 v = dw2[q];
        dwl[2 * q]     = v.x;
        dwl[2 * q + 1] = v.y;
    }

    // phase A: S-chain + interp coordinates (envelope math is off-chain ILP)
    float Sarr[N_STEPS + 1];
    float u[N_STEPS];
    Sarr[0] = 100.0f;
    #pragma unroll
    for (int i = 0; i < N_STEPS; i++) {
        float S = Sarr[i];
        float lo, hi;
        step_range(i, lo, hi);
        float uu = (S - lo) * (nsm1 / (hi - lo));
        u[i] = fminf(fmaxf(uu, 0.0f), nsm1);
        float dS = S * fmaf(0.2f, dwl[i], rdt);
        Sarr[i + 1] = S + dS;
    }

    // phase B: Y-chain with LDS gathers (addresses all ready)
    float Y = Y0[0];
    #pragma unroll
    for (int i = 0; i < N_STEPS; i++) {
        float uu = u[i];
        int jj = (int)uu;
        jj = min(jj, NS - 2);
        float f = uu - (float)jj;
        const float* row = stab + i * NS;
        float z0 = row[jj];
        float z1 = row[jj + 1];
        float z = fmaf(f, z1 - z0, z0);
        float S  = Sarr[i];
        float dS = Sarr[i + 1] - S;
        Y = Y + rdt * (Y - z * S) + z * dS;
    }
    out[p] = Y;
    out[B_PATHS + p] = Sarr[N_STEPS];
}

extern "C" void kernel_launch(void* const* d_in, const int* in_sizes, int n_in,
                              void* d_out, int out_size, void* d_ws, size_t ws_size,
                              hipStream_t stream)
{
    const float* dw  = (const float*)d_in[0];
    const float* W1  = (const float*)d_in[2];
    const float* b1  = (const float*)d_in[3];
    const float* g1  = (const float*)d_in[4];
    const float* be1 = (const float*)d_in[5];
    const float* W2  = (const float*)d_in[6];
    const float* b2  = (const float*)d_in[7];
    const float* g2  = (const float*)d_in[8];
    const float* be2 = (const float*)d_in[9];
    const float* W3  = (const float*)d_in[10];
    const float* b3  = (const float*)d_in[11];
    const float* Y0  = (const float*)d_in[12];
    float* out   = (float*)d_out;
    float* table = (float*)d_ws;          // 50 KB used

    void* args[] = {
        (void*)&dw,
        (void*)&W1, (void*)&b1, (void*)&g1, (void*)&be1,
        (void*)&W2, (void*)&b2, (void*)&g2, (void*)&be2,
        (void*)&W3, (void*)&b3, (void*)&Y0,
        (void*)&table, (void*)&out
    };
    hipLaunchCooperativeKernel((const void*)fused_kernel,
                               dim3(NBLK), dim3(64), args, 0, stream);
}

// Round 9
// 94.382 us; speedup vs baseline: 1.8852x; 1.8852x over previous
//
#include <hip/hip_runtime.h>

#define B_PATHS 32768
#define N_STEPS 50
#define H 64
#define NS 256             // table points per step; 50*256*4 = 50 KB LDS in sim
#define EV 8               // evals per wave in table build -> 50*(256/8)=1600 blocks

static __device__ __forceinline__ float gelu_f(float x) {
    // tanh-form GELU: max abs err vs exact-erf ~2e-4
    float x2 = x * x;
    float u  = x * fmaf(x2, 0.044715f * 0.7978845608f, 0.7978845608f);
    float e  = exp2f(u * -2.885390081777927f);   // e^{-2u}
    return x / (1.0f + e);
}

static __device__ __forceinline__ float sigmoid_f(float x) {
    float e = exp2f(x * -1.4426950408889634f);
    return 1.0f / (1.0f + e);
}

// Analytic per-step S envelope (covers 32k-path extremes ~4.2 sigma with 8-sigma bound).
static __device__ __forceinline__ void step_range(int i, float& lo, float& hi) {
    const float sd = 0.2f * 0.14142135623f;     // SIGMA * sqrt(DT)
    float w = fmaf(8.0f * sd, sqrtf((float)i), 0.05f);
    lo = 100.0f * expf(-w);
    hi = 100.0f * expf(w);
}

// Wave64 sum via DPP inclusive scan (VALU pipe) — the AMDGPUAtomicOptimizer sequence:
// row_shr:1,2,4,8 (dst[lane]=src[lane-k]; row sums land in lanes 15/31/47/63),
// row_bcast:15 (lane31 <- +row0sum, lane63 <- +row2sum),
// row_bcast:31 (lane63 <- +row0+row1) => lane 63 holds the wave total.
// old=0 + bound_ctrl=1 makes invalid-source lanes read the additive identity.
// N independent chains interleave for ILP; total broadcast via readlane 63.
template <int N>
static __device__ __forceinline__ void wave_sumN(float (&v)[N]) {
#define DPP_STAGE(CTRL)                                                                  \
    {                                                                                    \
        float t[N];                                                                      \
        _Pragma("unroll")                                                                \
        for (int e = 0; e < N; e++)                                                      \
            t[e] = __int_as_float(__builtin_amdgcn_update_dpp(                           \
                0, __float_as_int(v[e]), CTRL, 0xf, 0xf, true));                         \
        _Pragma("unroll")                                                                \
        for (int e = 0; e < N; e++) v[e] += t[e];                                        \
    }
    DPP_STAGE(0x111)   // row_shr:1
    DPP_STAGE(0x112)   // row_shr:2
    DPP_STAGE(0x114)   // row_shr:4
    DPP_STAGE(0x118)   // row_shr:8
    DPP_STAGE(0x142)   // row_bcast:15
    DPP_STAGE(0x143)   // row_bcast:31
#undef DPP_STAGE
    #pragma unroll
    for (int e = 0; e < N; e++)
        v[e] = __int_as_float(__builtin_amdgcn_readlane(__float_as_int(v[e]), 63));
}

// ---------------- pass 1: tabulate zeta_i(s), weight-stationary + DPP ----------------
// Lane n owns neuron n; W2 column n in 64 VGPRs (loaded once per wave). LN reductions
// via DPP. Layer-2 broadcast of hg via LDS: 1 ds_write + 16 wave-uniform ds_read_b128
// per eval (same-address broadcast, conflict-free) -> no readlane chains.
__global__ __launch_bounds__(64) void table_kernel(
    const float* __restrict__ W1, const float* __restrict__ b1,
    const float* __restrict__ g1, const float* __restrict__ be1,
    const float* __restrict__ W2, const float* __restrict__ b2,
    const float* __restrict__ g2, const float* __restrict__ be2,
    const float* __restrict__ W3, const float* __restrict__ b3,
    float* __restrict__ table)
{
    __shared__ float shg[EV * H];        // 2 KB

    int lane = threadIdx.x;
    int i  = blockIdx.x >> 5;            // step index (32 blocks per step)
    int j0 = (blockIdx.x & 31) * EV;     // first table point of this wave

    float w1a = W1[lane], w1b = W1[H + lane], bb1 = b1[lane];
    float gg1 = g1[lane], bbe1 = be1[lane];
    float bb2 = b2[lane], gg2 = g2[lane], bbe2 = be2[lane];
    float w3  = W3[lane];
    float b3s = b3[0];

    float w2c[H];                        // W2 column `lane`: coalesced, once
    #pragma unroll
    for (int k = 0; k < H; k++) w2c[k] = W2[k * H + lane];

    float lo, hi;
    step_range(i, lo, hi);
    float x1  = (float)i * 0.02f;        // == t_grid row value, bit-exact
    float dsg = (hi - lo) * (1.0f / (float)(NS - 1));

    // ---- layer 1 + LN1 + gelu ----
    float h[EV], s1[EV];
    #pragma unroll
    for (int e = 0; e < EV; e++) {
        float s  = fmaf(dsg, (float)(j0 + e), lo);
        h[e] = fmaf(s * 0.01f, w1a, fmaf(x1, w1b, bb1));
        s1[e] = h[e];
    }
    wave_sumN<EV>(s1);
    float d[EV], vv[EV];
    #pragma unroll
    for (int e = 0; e < EV; e++) { d[e] = h[e] - s1[e] * (1.0f / H); vv[e] = d[e] * d[e]; }
    wave_sumN<EV>(vv);
    #pragma unroll
    for (int e = 0; e < EV; e++) {
        float rstd = rsqrtf(fmaf(vv[e], 1.0f / H, 1e-5f));
        shg[e * H + lane] = gelu_f(fmaf(d[e] * rstd, gg1, bbe1));
    }
    __syncthreads();                     // single wave: just orders LDS write->read

    // ---- layer 2: acc[e] = sum_k hg[e][k] * w2c[k], hg via wave-uniform b128 reads ----
    float acc[EV];
    #pragma unroll
    for (int e = 0; e < EV; e++) acc[e] = bb2;
    #pragma unroll
    for (int q = 0; q < H / 4; q++) {
        float4 hv[EV];
        #pragma unroll
        for (int e = 0; e < EV; e++) hv[e] = ((const float4*)(shg + e * H))[q];
        #pragma unroll
        for (int e = 0; e < EV; e++) {
            acc[e] = fmaf(hv[e].x, w2c[4 * q + 0], acc[e]);
            acc[e] = fmaf(hv[e].y, w2c[4 * q + 1], acc[e]);
            acc[e] = fmaf(hv[e].z, w2c[4 * q + 2], acc[e]);
            acc[e] = fmaf(hv[e].w, w2c[4 * q + 3], acc[e]);
        }
    }

    // ---- LN2 + gelu + layer 3 + sigmoid ----
    float s2[EV];
    #pragma unroll
    for (int e = 0; e < EV; e++) s2[e] = acc[e];
    wave_sumN<EV>(s2);
    float d2[EV], v2[EV];
    #pragma unroll
    for (int e = 0; e < EV; e++) { d2[e] = acc[e] - s2[e] * (1.0f / H); v2[e] = d2[e] * d2[e]; }
    wave_sumN<EV>(v2);
    float zf[EV];
    #pragma unroll
    for (int e = 0; e < EV; e++) {
        float rstd = rsqrtf(fmaf(v2[e], 1.0f / H, 1e-5f));
        zf[e] = gelu_f(fmaf(d2[e] * rstd, gg2, bbe2)) * w3;
    }
    wave_sumN<EV>(zf);

    // lane e stores eval e (select chain avoids runtime-indexed register array)
    float zo = sigmoid_f(zf[0] + b3s);
    #pragma unroll
    for (int e = 1; e < EV; e++) {
        float z = sigmoid_f(zf[e] + b3s);
        zo = (lane == e) ? z : zo;
    }
    if (lane < EV) table[i * NS + j0 + lane] = zo;
}

// ---------------- pass 2: simulate paths, table gathered from LDS ----------------
// 512 blocks x 64 threads. Envelope recomputed analytically (no global ranges).
__global__ __launch_bounds__(64) void sim_kernel(const float* __restrict__ dw,
                                                 const float* __restrict__ table,
                                                 const float* __restrict__ Y0,
                                                 float* __restrict__ out)
{
    __shared__ float stab[N_STEPS * NS];   // 50 KB

    int lane = threadIdx.x;

    const float4* tg = (const float4*)table;
    float4* ts = (float4*)stab;
    #pragma unroll
    for (int q = 0; q < (N_STEPS * NS / 4) / 64; q++)   // 50 float4 per lane
        ts[q * 64 + lane] = tg[q * 64 + lane];
    __syncthreads();

    int p = blockIdx.x * 64 + lane;
    const float rdt = 0.05f * 0.02f;
    const float nsm1 = (float)(NS - 1);

    float dwl[N_STEPS];
    const float2* dw2 = (const float2*)(dw + p * N_STEPS);
    #pragma unroll
    for (int q = 0; q < N_STEPS / 2; q++) {
        float2 v = dw2[q];
        dwl[2 * q]     = v.x;
        dwl[2 * q + 1] = v.y;
    }

    // phase A: S-chain + interp coordinates (envelope math is off-chain ILP)
    float Sarr[N_STEPS + 1];
    float u[N_STEPS];
    Sarr[0] = 100.0f;
    #pragma unroll
    for (int i = 0; i < N_STEPS; i++) {
        float S = Sarr[i];
        float lo, hi;
        step_range(i, lo, hi);
        float uu = (S - lo) * (nsm1 / (hi - lo));
        u[i] = fminf(fmaxf(uu, 0.0f), nsm1);
        float dS = S * fmaf(0.2f, dwl[i], rdt);
        Sarr[i + 1] = S + dS;
    }

    // phase B: Y-chain with LDS gathers (addresses all ready)
    float Y = Y0[0];
    #pragma unroll
    for (int i = 0; i < N_STEPS; i++) {
        float uu = u[i];
        int jj = (int)uu;
        jj = min(jj, NS - 2);
        float f = uu - (float)jj;
        const float* row = stab + i * NS;
        float z0 = row[jj];
        float z1 = row[jj + 1];
        float z = fmaf(f, z1 - z0, z0);
        float S  = Sarr[i];
        float dS = Sarr[i + 1] - S;
        Y = Y + rdt * (Y - z * S) + z * dS;
    }
    out[p] = Y;
    out[B_PATHS + p] = Sarr[N_STEPS];
}

extern "C" void kernel_launch(void* const* d_in, const int* in_sizes, int n_in,
                              void* d_out, int out_size, void* d_ws, size_t ws_size,
                              hipStream_t stream)
{
    const float* dw  = (const float*)d_in[0];
    const float* W1  = (const float*)d_in[2];
    const float* b1  = (const float*)d_in[3];
    const float* g1  = (const float*)d_in[4];
    const float* be1 = (const float*)d_in[5];
    const float* W2  = (const float*)d_in[6];
    const float* b2  = (const float*)d_in[7];
    const float* g2  = (const float*)d_in[8];
    const float* be2 = (const float*)d_in[9];
    const float* W3  = (const float*)d_in[10];
    const float* b3  = (const float*)d_in[11];
    const float* Y0  = (const float*)d_in[12];
    float* out   = (float*)d_out;
    float* table = (float*)d_ws;           // 50 KB used

    table_kernel<<<N_STEPS * (NS / EV), 64, 0, stream>>>(
        W1, b1, g1, be1, W2, b2, g2, be2, W3, b3, table);
    sim_kernel<<<B_PATHS / 64, 64, 0, stream>>>(dw, table, Y0, out);
}

// Round 10
// 92.413 us; speedup vs baseline: 1.9254x; 1.0213x over previous
//
#include <hip/hip_runtime.h>

#define B_PATHS 32768
#define N_STEPS 50
#define H 64
#define NS 256             // table points per step; 50*256*4 = 50 KB LDS in sim
#define EV 4               // evals per wave: keeps VGPR ~100 (w2c[64]+4-wide arrays),
                           // NO scratch spills (r7 profile showed EV=13 spilling: 349KB
                           // WRITE for a 50KB table). 50*(256/4)=3200 blocks.

static __device__ __forceinline__ float gelu_f(float x) {
    // tanh-form GELU: max abs err vs exact-erf ~2e-4
    float x2 = x * x;
    float u  = x * fmaf(x2, 0.044715f * 0.7978845608f, 0.7978845608f);
    float e  = exp2f(u * -2.885390081777927f);   // e^{-2u}
    return x / (1.0f + e);
}

static __device__ __forceinline__ float sigmoid_f(float x) {
    float e = exp2f(x * -1.4426950408889634f);
    return 1.0f / (1.0f + e);
}

// Analytic per-step S envelope (covers 32k-path extremes ~4.2 sigma with 8-sigma bound).
static __device__ __forceinline__ void step_range(int i, float& lo, float& hi) {
    const float sd = 0.2f * 0.14142135623f;     // SIGMA * sqrt(DT)
    float w = fmaf(8.0f * sd, sqrtf((float)i), 0.05f);
    lo = 100.0f * expf(-w);
    hi = 100.0f * expf(w);
}

// Wave64 sum via DPP inclusive scan (VALU pipe) — AMDGPUAtomicOptimizer sequence:
// row_shr:1,2,4,8 then row_bcast:15, row_bcast:31; lane 63 holds the total.
// old=0 + bound_ctrl=1: invalid-source lanes read the additive identity.
template <int N>
static __device__ __forceinline__ void wave_sumN(float (&v)[N]) {
#define DPP_STAGE(CTRL)                                                                  \
    {                                                                                    \
        float t[N];                                                                      \
        _Pragma("unroll")                                                                \
        for (int e = 0; e < N; e++)                                                      \
            t[e] = __int_as_float(__builtin_amdgcn_update_dpp(                           \
                0, __float_as_int(v[e]), CTRL, 0xf, 0xf, true));                         \
        _Pragma("unroll")                                                                \
        for (int e = 0; e < N; e++) v[e] += t[e];                                        \
    }
    DPP_STAGE(0x111)   // row_shr:1
    DPP_STAGE(0x112)   // row_shr:2
    DPP_STAGE(0x114)   // row_shr:4
    DPP_STAGE(0x118)   // row_shr:8
    DPP_STAGE(0x142)   // row_bcast:15
    DPP_STAGE(0x143)   // row_bcast:31
#undef DPP_STAGE
    #pragma unroll
    for (int e = 0; e < N; e++)
        v[e] = __int_as_float(__builtin_amdgcn_readlane(__float_as_int(v[e]), 63));
}

// ---------------- pass 1: tabulate zeta_i(s), weight-stationary + DPP ----------------
// Lane n owns neuron n; W2 column n in 64 VGPRs (loaded once per wave, L2-hot after
// the first blocks). LN reductions on the VALU pipe (DPP). Layer-2 hg broadcast via
// LDS: 1 ds_write + 16 wave-uniform ds_read_b128 per eval (same-address broadcast).
__global__ __launch_bounds__(64) void table_kernel(
    const float* __restrict__ W1, const float* __restrict__ b1,
    const float* __restrict__ g1, const float* __restrict__ be1,
    const float* __restrict__ W2, const float* __restrict__ b2,
    const float* __restrict__ g2, const float* __restrict__ be2,
    const float* __restrict__ W3, const float* __restrict__ b3,
    float* __restrict__ table)
{
    __shared__ float shg[EV * H];        // 1 KB

    int lane = threadIdx.x;
    int i  = blockIdx.x >> 6;            // step index (64 blocks per step, NS/EV=64)
    int j0 = (blockIdx.x & 63) * EV;     // first table point of this wave

    float w1a = W1[lane], w1b = W1[H + lane], bb1 = b1[lane];
    float gg1 = g1[lane], bbe1 = be1[lane];
    float bb2 = b2[lane], gg2 = g2[lane], bbe2 = be2[lane];
    float w3  = W3[lane];
    float b3s = b3[0];

    float w2c[H];                        // W2 column `lane`: coalesced, once
    #pragma unroll
    for (int k = 0; k < H; k++) w2c[k] = W2[k * H + lane];

    float lo, hi;
    step_range(i, lo, hi);
    float x1  = (float)i * 0.02f;        // == t_grid row value, bit-exact
    float dsg = (hi - lo) * (1.0f / (float)(NS - 1));

    // ---- layer 1 + LN1 + gelu ----
    float h[EV], s1[EV];
    #pragma unroll
    for (int e = 0; e < EV; e++) {
        float s  = fmaf(dsg, (float)(j0 + e), lo);
        h[e] = fmaf(s * 0.01f, w1a, fmaf(x1, w1b, bb1));
        s1[e] = h[e];
    }
    wave_sumN<EV>(s1);
    float d[EV], vv[EV];
    #pragma unroll
    for (int e = 0; e < EV; e++) { d[e] = h[e] - s1[e] * (1.0f / H); vv[e] = d[e] * d[e]; }
    wave_sumN<EV>(vv);
    #pragma unroll
    for (int e = 0; e < EV; e++) {
        float rstd = rsqrtf(fmaf(vv[e], 1.0f / H, 1e-5f));
        shg[e * H + lane] = gelu_f(fmaf(d[e] * rstd, gg1, bbe1));
    }
    __syncthreads();                     // single wave: just orders LDS write->read

    // ---- layer 2: acc[e] = sum_k hg[e][k] * w2c[k], hg via wave-uniform b128 reads ----
    float acc[EV];
    #pragma unroll
    for (int e = 0; e < EV; e++) acc[e] = bb2;
    #pragma unroll
    for (int q = 0; q < H / 4; q++) {
        float4 hv[EV];
        #pragma unroll
        for (int e = 0; e < EV; e++) hv[e] = ((const float4*)(shg + e * H))[q];
        #pragma unroll
        for (int e = 0; e < EV; e++) {
            acc[e] = fmaf(hv[e].x, w2c[4 * q + 0], acc[e]);
            acc[e] = fmaf(hv[e].y, w2c[4 * q + 1], acc[e]);
            acc[e] = fmaf(hv[e].z, w2c[4 * q + 2], acc[e]);
            acc[e] = fmaf(hv[e].w, w2c[4 * q + 3], acc[e]);
        }
    }

    // ---- LN2 + gelu + layer 3 + sigmoid ----
    float s2[EV];
    #pragma unroll
    for (int e = 0; e < EV; e++) s2[e] = acc[e];
    wave_sumN<EV>(s2);
    float d2[EV], v2[EV];
    #pragma unroll
    for (int e = 0; e < EV; e++) { d2[e] = acc[e] - s2[e] * (1.0f / H); v2[e] = d2[e] * d2[e]; }
    wave_sumN<EV>(v2);
    float zf[EV];
    #pragma unroll
    for (int e = 0; e < EV; e++) {
        float rstd = rsqrtf(fmaf(v2[e], 1.0f / H, 1e-5f));
        zf[e] = gelu_f(fmaf(d2[e] * rstd, gg2, bbe2)) * w3;
    }
    wave_sumN<EV>(zf);

    // lane e stores eval e (select chain avoids runtime-indexed register array)
    float zo = sigmoid_f(zf[0] + b3s);
    #pragma unroll
    for (int e = 1; e < EV; e++) {
        float z = sigmoid_f(zf[e] + b3s);
        zo = (lane == e) ? z : zo;
    }
    if (lane < EV) table[i * NS + j0 + lane] = zo;
}

// ---------------- pass 2: simulate paths, table gathered from LDS ----------------
// 512 blocks x 64 threads. Envelope recomputed analytically (no global ranges).
__global__ __launch_bounds__(64) void sim_kernel(const float* __restrict__ dw,
                                                 const float* __restrict__ table,
                                                 const float* __restrict__ Y0,
                                                 float* __restrict__ out)
{
    __shared__ float stab[N_STEPS * NS];   // 50 KB

    int lane = threadIdx.x;

    const float4* tg = (const float4*)table;
    float4* ts = (float4*)stab;
    #pragma unroll
    for (int q = 0; q < (N_STEPS * NS / 4) / 64; q++)   // 50 float4 per lane
        ts[q * 64 + lane] = tg[q * 64 + lane];
    __syncthreads();

    int p = blockIdx.x * 64 + lane;
    const float rdt = 0.05f * 0.02f;
    const float nsm1 = (float)(NS - 1);

    float dwl[N_STEPS];
    const float2* dw2 = (const float2*)(dw + p * N_STEPS);
    #pragma unroll
    for (int q = 0; q < N_STEPS / 2; q++) {
        float2 v = dw2[q];
        dwl[2 * q]     = v.x;
        dwl[2 * q + 1] = v.y;
    }

    // phase A: S-chain + interp coordinates (envelope math is off-chain ILP)
    float Sarr[N_STEPS + 1];
    float u[N_STEPS];
    Sarr[0] = 100.0f;
    #pragma unroll
    for (int i = 0; i < N_STEPS; i++) {
        float S = Sarr[i];
        float lo, hi;
        step_range(i, lo, hi);
        float uu = (S - lo) * (nsm1 / (hi - lo));
        u[i] = fminf(fmaxf(uu, 0.0f), nsm1);
        float dS = S * fmaf(0.2f, dwl[i], rdt);
        Sarr[i + 1] = S + dS;
    }

    // phase B: Y-chain with LDS gathers (addresses all ready)
    float Y = Y0[0];
    #pragma unroll
    for (int i = 0; i < N_STEPS; i++) {
        float uu = u[i];
        int jj = (int)uu;
        jj = min(jj, NS - 2);
        float f = uu - (float)jj;
        const float* row = stab + i * NS;
        float z0 = row[jj];
        float z1 = row[jj + 1];
        float z = fmaf(f, z1 - z0, z0);
        float S  = Sarr[i];
        float dS = Sarr[i + 1] - S;
        Y = Y + rdt * (Y - z * S) + z * dS;
    }
    out[p] = Y;
    out[B_PATHS + p] = Sarr[N_STEPS];
}

extern "C" void kernel_launch(void* const* d_in, const int* in_sizes, int n_in,
                              void* d_out, int out_size, void* d_ws, size_t ws_size,
                              hipStream_t stream)
{
    const float* dw  = (const float*)d_in[0];
    const float* W1  = (const float*)d_in[2];
    const float* b1  = (const float*)d_in[3];
    const float* g1  = (const float*)d_in[4];
    const float* be1 = (const float*)d_in[5];
    const float* W2  = (const float*)d_in[6];
    const float* b2  = (const float*)d_in[7];
    const float* g2  = (const float*)d_in[8];
    const float* be2 = (const float*)d_in[9];
    const float* W3  = (const float*)d_in[10];
    const float* b3  = (const float*)d_in[11];
    const float* Y0  = (const float*)d_in[12];
    float* out   = (float*)d_out;
    float* table = (float*)d_ws;           // 50 KB used

    table_kernel<<<N_STEPS * (NS / EV), 64, 0, stream>>>(
        W1, b1, g1, be1, W2, b2, g2, be2, W3, b3, table);
    sim_kernel<<<B_PATHS / 64, 64, 0, stream>>>(dw, table, Y0, out);
}

// Round 11
// 88.738 us; speedup vs baseline: 2.0051x; 1.0414x over previous
//
#include <hip/hip_runtime.h>

#define B_PATHS 32768
#define N_STEPS 50
#define H 64
#define NS 128             // table points per step; 50*128*4 = 25 KB LDS in sim.
                           // absmax was interp-insensitive from NS=1024..256 (0.25 flat,
                           // dominated by tanh-GELU systematic); NS=128 err ~1e-3 << 4.92.
#define EV 4               // evals per wave: VGPR ~100, no scratch spills (r7 lesson)

static __device__ __forceinline__ float gelu_f(float x) {
    // tanh-form GELU: max abs err vs exact-erf ~2e-4
    float x2 = x * x;
    float u  = x * fmaf(x2, 0.044715f * 0.7978845608f, 0.7978845608f);
    float e  = exp2f(u * -2.885390081777927f);   // e^{-2u}
    return x / (1.0f + e);
}

static __device__ __forceinline__ float sigmoid_f(float x) {
    float e = exp2f(x * -1.4426950408889634f);
    return 1.0f / (1.0f + e);
}

// Analytic per-step S envelope (covers 32k-path extremes ~4.2 sigma with 8-sigma bound).
static __device__ __forceinline__ void step_range(int i, float& lo, float& hi) {
    const float sd = 0.2f * 0.14142135623f;     // SIGMA * sqrt(DT)
    float w = fmaf(8.0f * sd, sqrtf((float)i), 0.05f);
    lo = 100.0f * expf(-w);
    hi = 100.0f * expf(w);
}

// Wave64 sum via DPP inclusive scan (VALU pipe) — AMDGPUAtomicOptimizer sequence:
// row_shr:1,2,4,8 then row_bcast:15, row_bcast:31; lane 63 holds the total.
// old=0 + bound_ctrl=1: invalid-source lanes read the additive identity.
template <int N>
static __device__ __forceinline__ void wave_sumN(float (&v)[N]) {
#define DPP_STAGE(CTRL)                                                                  \
    {                                                                                    \
        float t[N];                                                                      \
        _Pragma("unroll")                                                                \
        for (int e = 0; e < N; e++)                                                      \
            t[e] = __int_as_float(__builtin_amdgcn_update_dpp(                           \
                0, __float_as_int(v[e]), CTRL, 0xf, 0xf, true));                         \
        _Pragma("unroll")                                                                \
        for (int e = 0; e < N; e++) v[e] += t[e];                                        \
    }
    DPP_STAGE(0x111)   // row_shr:1
    DPP_STAGE(0x112)   // row_shr:2
    DPP_STAGE(0x114)   // row_shr:4
    DPP_STAGE(0x118)   // row_shr:8
    DPP_STAGE(0x142)   // row_bcast:15
    DPP_STAGE(0x143)   // row_bcast:31
#undef DPP_STAGE
    #pragma unroll
    for (int e = 0; e < N; e++)
        v[e] = __int_as_float(__builtin_amdgcn_readlane(__float_as_int(v[e]), 63));
}

// ---------------- pass 1: tabulate zeta_i(s), weight-stationary + DPP ----------------
// Lane n owns neuron n; W2 column n in 64 VGPRs (loaded once per wave, L2-hot after
// the first blocks). LN reductions on the VALU pipe (DPP). Layer-2 hg broadcast via
// LDS: 1 ds_write + 16 wave-uniform ds_read_b128 per eval (same-address broadcast).
// 50*(128/4) = 1600 blocks of one wave.
__global__ __launch_bounds__(64) void table_kernel(
    const float* __restrict__ W1, const float* __restrict__ b1,
    const float* __restrict__ g1, const float* __restrict__ be1,
    const float* __restrict__ W2, const float* __restrict__ b2,
    const float* __restrict__ g2, const float* __restrict__ be2,
    const float* __restrict__ W3, const float* __restrict__ b3,
    float* __restrict__ table)
{
    __shared__ float shg[EV * H];        // 1 KB

    int lane = threadIdx.x;
    int i  = blockIdx.x >> 5;            // step index (32 blocks per step, NS/EV=32)
    int j0 = (blockIdx.x & 31) * EV;     // first table point of this wave

    float w1a = W1[lane], w1b = W1[H + lane], bb1 = b1[lane];
    float gg1 = g1[lane], bbe1 = be1[lane];
    float bb2 = b2[lane], gg2 = g2[lane], bbe2 = be2[lane];
    float w3  = W3[lane];
    float b3s = b3[0];

    float w2c[H];                        // W2 column `lane`: coalesced, once
    #pragma unroll
    for (int k = 0; k < H; k++) w2c[k] = W2[k * H + lane];

    float lo, hi;
    step_range(i, lo, hi);
    float x1  = (float)i * 0.02f;        // == t_grid row value, bit-exact
    float dsg = (hi - lo) * (1.0f / (float)(NS - 1));

    // ---- layer 1 + LN1 + gelu ----
    float h[EV], s1[EV];
    #pragma unroll
    for (int e = 0; e < EV; e++) {
        float s  = fmaf(dsg, (float)(j0 + e), lo);
        h[e] = fmaf(s * 0.01f, w1a, fmaf(x1, w1b, bb1));
        s1[e] = h[e];
    }
    wave_sumN<EV>(s1);
    float d[EV], vv[EV];
    #pragma unroll
    for (int e = 0; e < EV; e++) { d[e] = h[e] - s1[e] * (1.0f / H); vv[e] = d[e] * d[e]; }
    wave_sumN<EV>(vv);
    #pragma unroll
    for (int e = 0; e < EV; e++) {
        float rstd = rsqrtf(fmaf(vv[e], 1.0f / H, 1e-5f));
        shg[e * H + lane] = gelu_f(fmaf(d[e] * rstd, gg1, bbe1));
    }
    __syncthreads();                     // single wave: just orders LDS write->read

    // ---- layer 2: acc[e] = sum_k hg[e][k] * w2c[k], hg via wave-uniform b128 reads ----
    float acc[EV];
    #pragma unroll
    for (int e = 0; e < EV; e++) acc[e] = bb2;
    #pragma unroll
    for (int q = 0; q < H / 4; q++) {
        float4 hv[EV];
        #pragma unroll
        for (int e = 0; e < EV; e++) hv[e] = ((const float4*)(shg + e * H))[q];
        #pragma unroll
        for (int e = 0; e < EV; e++) {
            acc[e] = fmaf(hv[e].x, w2c[4 * q + 0], acc[e]);
            acc[e] = fmaf(hv[e].y, w2c[4 * q + 1], acc[e]);
            acc[e] = fmaf(hv[e].z, w2c[4 * q + 2], acc[e]);
            acc[e] = fmaf(hv[e].w, w2c[4 * q + 3], acc[e]);
        }
    }

    // ---- LN2 + gelu + layer 3 + sigmoid ----
    float s2[EV];
    #pragma unroll
    for (int e = 0; e < EV; e++) s2[e] = acc[e];
    wave_sumN<EV>(s2);
    float d2[EV], v2[EV];
    #pragma unroll
    for (int e = 0; e < EV; e++) { d2[e] = acc[e] - s2[e] * (1.0f / H); v2[e] = d2[e] * d2[e]; }
    wave_sumN<EV>(v2);
    float zf[EV];
    #pragma unroll
    for (int e = 0; e < EV; e++) {
        float rstd = rsqrtf(fmaf(v2[e], 1.0f / H, 1e-5f));
        zf[e] = gelu_f(fmaf(d2[e] * rstd, gg2, bbe2)) * w3;
    }
    wave_sumN<EV>(zf);

    // lane e stores eval e (select chain avoids runtime-indexed register array)
    float zo = sigmoid_f(zf[0] + b3s);
    #pragma unroll
    for (int e = 1; e < EV; e++) {
        float z = sigmoid_f(zf[e] + b3s);
        zo = (lane == e) ? z : zo;
    }
    if (lane < EV) table[i * NS + j0 + lane] = zo;
}

// ---------------- pass 2: simulate paths, table gathered from LDS ----------------
// 512 blocks x 64 threads. Staging issued first, then dw preload + S-chain run
// UNDER the staging latency; __syncthreads only before the Y-chain needs the table.
__global__ __launch_bounds__(64) void sim_kernel(const float* __restrict__ dw,
                                                 const float* __restrict__ table,
                                                 const float* __restrict__ Y0,
                                                 float* __restrict__ out)
{
    __shared__ float stab[N_STEPS * NS];   // 25 KB

    int lane = threadIdx.x;

    // issue staging (25 float4 per lane); latency hides under phase A below
    const float4* tg = (const float4*)table;
    float4* ts = (float4*)stab;
    #pragma unroll
    for (int q = 0; q < (N_STEPS * NS / 4) / 64; q++)   // 25
        ts[q * 64 + lane] = tg[q * 64 + lane];

    int p = blockIdx.x * 64 + lane;
    const float rdt = 0.05f * 0.02f;
    const float nsm1 = (float)(NS - 1);

    float dwl[N_STEPS];
    const float2* dw2 = (const float2*)(dw + p * N_STEPS);
    #pragma unroll
    for (int q = 0; q < N_STEPS / 2; q++) {
        float2 v = dw2[q];
        dwl[2 * q]     = v.x;
        dwl[2 * q + 1] = v.y;
    }

    // phase A: S-chain + interp coordinates (envelope math is off-chain ILP)
    float Sarr[N_STEPS + 1];
    float u[N_STEPS];
    Sarr[0] = 100.0f;
    #pragma unroll
    for (int i = 0; i < N_STEPS; i++) {
        float S = Sarr[i];
        float lo, hi;
        step_range(i, lo, hi);
        float uu = (S - lo) * (nsm1 / (hi - lo));
        u[i] = fminf(fmaxf(uu, 0.0f), nsm1);
        float dS = S * fmaf(0.2f, dwl[i], rdt);
        Sarr[i + 1] = S + dS;
    }

    __syncthreads();                     // staging complete; table needed from here

    // phase B: Y-chain with LDS gathers (addresses all ready)
    float Y = Y0[0];
    #pragma unroll
    for (int i = 0; i < N_STEPS; i++) {
        float uu = u[i];
        int jj = (int)uu;
        jj = min(jj, NS - 2);
        float f = uu - (float)jj;
        const float* row = stab + i * NS;
        float z0 = row[jj];
        float z1 = row[jj + 1];
        float z = fmaf(f, z1 - z0, z0);
        float S  = Sarr[i];
        float dS = Sarr[i + 1] - S;
        Y = Y + rdt * (Y - z * S) + z * dS;
    }
    out[p] = Y;
    out[B_PATHS + p] = Sarr[N_STEPS];
}

extern "C" void kernel_launch(void* const* d_in, const int* in_sizes, int n_in,
                              void* d_out, int out_size, void* d_ws, size_t ws_size,
                              hipStream_t stream)
{
    const float* dw  = (const float*)d_in[0];
    const float* W1  = (const float*)d_in[2];
    const float* b1  = (const float*)d_in[3];
    const float* g1  = (const float*)d_in[4];
    const float* be1 = (const float*)d_in[5];
    const float* W2  = (const float*)d_in[6];
    const float* b2  = (const float*)d_in[7];
    const float* g2  = (const float*)d_in[8];
    const float* be2 = (const float*)d_in[9];
    const float* W3  = (const float*)d_in[10];
    const float* b3  = (const float*)d_in[11];
    const float* Y0  = (const float*)d_in[12];
    float* out   = (float*)d_out;
    float* table = (float*)d_ws;           // 25 KB used

    table_kernel<<<N_STEPS * (NS / EV), 64, 0, stream>>>(
        W1, b1, g1, be1, W2, b2, g2, be2, W3, b3, table);
    sim_kernel<<<B_PATHS / 64, 64, 0, stream>>>(dw, table, Y0, out);
}